// Round 5
// baseline (1323.289 us; speedup 1.0000x reference)
//
#include <hip/hip_runtime.h>
#include <hip/hip_cooperative_groups.h>
#include <math.h>

namespace cg = cooperative_groups;

#define HH 64
// Bucket = col >> 8 (256 nodes per bucket). Requires N <= 65536 (N=50000 here),
// also required by the 16-bit row packing in pairbuf, and NB <= 256 for k_scan.
#define BSH 8
#define BSZ 256

typedef _Float16 half_t;
typedef _Float16 half4_t __attribute__((ext_vector_type(4)));

// ---- shared-memory union: one phase at a time (grid.sync between phases) ----
struct GmSh  { float ws[32][HH]; float xs[32][68]; };   // 16896 B (max member)
struct ScSh  { int h[BSZ]; int cur[BSZ]; };
struct BcSh  { int lcnt[BSZ]; int ssc[BSZ]; int lcur[BSZ]; };
struct ScanSh{ int s[256]; };
struct FinSh { float semb[HH]; float slog[16]; };
union MegaSh { GmSh gm; ScSh sc; BcSh bc; ScanSh scan; FinSh fin; };

struct Params {
    const float* x;
    const int* row; const int* col; const int* batch;
    const float *W1, *b1, *W2, *b2, *W3, *b3, *Wm, *bm;
    float* logits; float* probs; float* node_emb; float* graph_emb;
    float* dinv; int* cnt; int* rowptr;
    int* bucket_cnt; int* bucket_base; int* bucket_cursor;
    float* sums; float* cnts;
    int* pairbuf; int* csr;
    half_t* bufA; half_t* bufB;
    int N, E, G, NB;
};

// ---------------- dense transform phase (W staged in 32-row slices) ----------
template<int FIN, bool SCALE, bool HIN>
__device__ __forceinline__ void gemm_phase(MegaSh& sh, const void* __restrict__ xin,
                                           const float* __restrict__ W,
                                           const float* __restrict__ dinv,
                                           half_t* __restrict__ out, int n) {
    const int tid = threadIdx.x;
    const int tx = tid & 15, ty = tid >> 4;
    const int rr0 = tid >> 3, cc = (tid & 7) * 4;
    const int ntiles = (n + 63) >> 6;
    for (int tile = blockIdx.x; tile < ntiles; tile += gridDim.x) {
        const int node0 = tile << 6;
        float acc[4][4] = {};
        for (int kc = 0; kc < FIN; kc += 32) {
            __syncthreads();
            for (int i = tid * 4; i < 32 * HH; i += 1024)
                *(float4*)&sh.gm.ws[0][i] = *(const float4*)&W[kc * HH + i];
            for (int rr = rr0; rr < 64; rr += 32) {
                float4 v = make_float4(0.f, 0.f, 0.f, 0.f);
                if (node0 + rr < n) {
                    if constexpr (HIN) {
                        half4_t hv = *(const half4_t*)((const half_t*)xin +
                                       (size_t)(node0 + rr) * FIN + kc + cc);
                        v = make_float4((float)hv.x, (float)hv.y, (float)hv.z, (float)hv.w);
                    } else {
                        v = *(const float4*)((const float*)xin +
                                       (size_t)(node0 + rr) * FIN + kc + cc);
                    }
                }
                sh.gm.xs[cc + 0][rr] = v.x;
                sh.gm.xs[cc + 1][rr] = v.y;
                sh.gm.xs[cc + 2][rr] = v.z;
                sh.gm.xs[cc + 3][rr] = v.w;
            }
            __syncthreads();
#pragma unroll 4
            for (int k = 0; k < 32; ++k) {
                float4 a4 = *(const float4*)&sh.gm.xs[k][ty * 4];
                float4 b4 = *(const float4*)&sh.gm.ws[k][tx * 4];
                acc[0][0] = fmaf(a4.x, b4.x, acc[0][0]);
                acc[0][1] = fmaf(a4.x, b4.y, acc[0][1]);
                acc[0][2] = fmaf(a4.x, b4.z, acc[0][2]);
                acc[0][3] = fmaf(a4.x, b4.w, acc[0][3]);
                acc[1][0] = fmaf(a4.y, b4.x, acc[1][0]);
                acc[1][1] = fmaf(a4.y, b4.y, acc[1][1]);
                acc[1][2] = fmaf(a4.y, b4.z, acc[1][2]);
                acc[1][3] = fmaf(a4.y, b4.w, acc[1][3]);
                acc[2][0] = fmaf(a4.z, b4.x, acc[2][0]);
                acc[2][1] = fmaf(a4.z, b4.y, acc[2][1]);
                acc[2][2] = fmaf(a4.z, b4.z, acc[2][2]);
                acc[2][3] = fmaf(a4.z, b4.w, acc[2][3]);
                acc[3][0] = fmaf(a4.w, b4.x, acc[3][0]);
                acc[3][1] = fmaf(a4.w, b4.y, acc[3][1]);
                acc[3][2] = fmaf(a4.w, b4.z, acc[3][2]);
                acc[3][3] = fmaf(a4.w, b4.w, acc[3][3]);
            }
        }
#pragma unroll
        for (int i = 0; i < 4; ++i) {
            int node = node0 + ty * 4 + i;
            if (node < n) {
                float d = SCALE ? dinv[node] : 1.f;
                half4_t o = {(half_t)(acc[i][0] * d), (half_t)(acc[i][1] * d),
                             (half_t)(acc[i][2] * d), (half_t)(acc[i][3] * d)};
                *(half4_t*)(out + (size_t)node * HH + tx * 4) = o;
            }
        }
    }
}

// ---------------- gather phase: quarter-wave, fp16 rows, fp32 accumulate ------
template<bool WEIGHTED, bool HOUT>
__device__ __forceinline__ void gather_phase(const half_t* __restrict__ lin,
                                             const int* __restrict__ csr,
                                             const int* __restrict__ rowptr,
                                             const int* __restrict__ cnt,
                                             const float* __restrict__ dinv,
                                             const float* __restrict__ b,
                                             void* __restrict__ hout, int n) {
    const int lane = threadIdx.x & 63;
    const int wv = threadIdx.x >> 6;
    const int q  = lane >> 4;
    const int fl = (lane & 15) * 4;
    const int ngrp = (n + 3) >> 2;
    for (int grp = blockIdx.x; grp < ngrp; grp += gridDim.x) {
        int node = grp * 4 + wv;
        if (node >= n) continue;              // wave-uniform guard
        int start = rowptr[node];
        int end = start + cnt[node];
        float di = dinv[node];

        float4 a0 = make_float4(0.f, 0.f, 0.f, 0.f);
        float4 a1 = make_float4(0.f, 0.f, 0.f, 0.f);

        for (int base = start; base < end; base += 64) {
            int m = end - base; if (m > 64) m = 64;
            int idx = base + lane;
            int   sv = (idx < end) ? csr[idx] : 0;
            float wvw;
            if (WEIGHTED) wvw = (idx < end) ? dinv[sv] : 0.f;
            else          wvw = (idx < end) ? 1.f : 0.f;
            for (int j = 0; j < m; j += 16) {
                int l = j + q * 4;
                int   s0 = __shfl(sv, l, 64);
                int   s1 = __shfl(sv, l + 1, 64);
                int   s2 = __shfl(sv, l + 2, 64);
                int   s3 = __shfl(sv, l + 3, 64);
                float w0 = __shfl(wvw, l, 64);
                float w1 = __shfl(wvw, l + 1, 64);
                float w2 = __shfl(wvw, l + 2, 64);
                float w3 = __shfl(wvw, l + 3, 64);
                half4_t v0 = *(const half4_t*)&lin[(size_t)s0 * HH + fl];
                half4_t v1 = *(const half4_t*)&lin[(size_t)s1 * HH + fl];
                half4_t v2 = *(const half4_t*)&lin[(size_t)s2 * HH + fl];
                half4_t v3 = *(const half4_t*)&lin[(size_t)s3 * HH + fl];
                a0.x = fmaf(w0, (float)v0.x, a0.x); a0.y = fmaf(w0, (float)v0.y, a0.y);
                a0.z = fmaf(w0, (float)v0.z, a0.z); a0.w = fmaf(w0, (float)v0.w, a0.w);
                a1.x = fmaf(w1, (float)v1.x, a1.x); a1.y = fmaf(w1, (float)v1.y, a1.y);
                a1.z = fmaf(w1, (float)v1.z, a1.z); a1.w = fmaf(w1, (float)v1.w, a1.w);
                a0.x = fmaf(w2, (float)v2.x, a0.x); a0.y = fmaf(w2, (float)v2.y, a0.y);
                a0.z = fmaf(w2, (float)v2.z, a0.z); a0.w = fmaf(w2, (float)v2.w, a0.w);
                a1.x = fmaf(w3, (float)v3.x, a1.x); a1.y = fmaf(w3, (float)v3.y, a1.y);
                a1.z = fmaf(w3, (float)v3.z, a1.z); a1.w = fmaf(w3, (float)v3.w, a1.w);
            }
        }
        float4 acc = make_float4(a0.x + a1.x, a0.y + a1.y, a0.z + a1.z, a0.w + a1.w);
#pragma unroll
        for (int off = 16; off < 64; off <<= 1) {
            acc.x += __shfl_xor(acc.x, off, 64);
            acc.y += __shfl_xor(acc.y, off, 64);
            acc.z += __shfl_xor(acc.z, off, 64);
            acc.w += __shfl_xor(acc.w, off, 64);
        }
        half4_t self = *(const half4_t*)&lin[(size_t)node * HH + fl];
        float sw = WEIGHTED ? di : 1.f;
        acc.x = fmaf(sw, (float)self.x, acc.x);
        acc.y = fmaf(sw, (float)self.y, acc.y);
        acc.z = fmaf(sw, (float)self.z, acc.z);
        acc.w = fmaf(sw, (float)self.w, acc.w);
        float4 b4 = *(const float4*)&b[fl];
        float4 v4 = make_float4(fmaf(di, acc.x, b4.x), fmaf(di, acc.y, b4.y),
                                fmaf(di, acc.z, b4.z), fmaf(di, acc.w, b4.w));
        float ss = v4.x * v4.x + v4.y * v4.y + v4.z * v4.z + v4.w * v4.w;
#pragma unroll
        for (int off = 1; off < 16; off <<= 1) ss += __shfl_xor(ss, off, 64);
        float inv = 1.f / fmaxf(sqrtf(ss), 1e-12f);
        v4.x = fmaxf(v4.x * inv, 0.f);
        v4.y = fmaxf(v4.y * inv, 0.f);
        v4.z = fmaxf(v4.z * inv, 0.f);
        v4.w = fmaxf(v4.w * inv, 0.f);
        if (q == 0) {
            if constexpr (HOUT) {
                half4_t o = {(half_t)v4.x, (half_t)v4.y, (half_t)v4.z, (half_t)v4.w};
                *(half4_t*)((half_t*)hout + (size_t)node * HH + fl) = o;
            } else {
                *(float4*)((float*)hout + (size_t)node * HH + fl) = v4;
            }
        }
    }
}

// ---------------- the whole pipeline in one cooperative kernel ----------------
__global__ __launch_bounds__(256, 4) void mega(Params p) {
    cg::grid_group grid = cg::this_grid();
    __shared__ MegaSh sh;
    const int tid = threadIdx.x;
    const int bid = blockIdx.x;
    const int nblk = gridDim.x;
    const int gthreads = nblk * 256;
    const int gtid = bid * 256 + tid;
    const int pb = (nblk < 256) ? nblk : 256;   // blocks participating in edge passes

    // P0: zero bucket_cnt + pooling sums/cnts
    for (int i = gtid; i < p.NB + 1; i += gthreads) p.bucket_cnt[i] = 0;
    {
        int pn = p.G * HH + p.G;
        for (int i = gtid; i < pn; i += gthreads) p.sums[i] = 0.f;
    }
    grid.sync();

    // P1: bucket histogram via LDS (no per-edge global atomics)
    if (bid < pb) {
        sh.sc.h[tid] = 0;
        __syncthreads();
        const int stride = pb * 256;
        for (int e = bid * 256 + tid; e < p.E; e += stride)
            atomicAdd(&sh.sc.h[p.col[e] >> BSH], 1);
        __syncthreads();
        if (tid < p.NB && sh.sc.h[tid]) atomicAdd(&p.bucket_cnt[tid], sh.sc.h[tid]);
    }
    grid.sync();

    // P2: exclusive scan of bucket counts (block 0; NB <= 256)
    if (bid == 0) {
        int v = (tid < p.NB) ? p.bucket_cnt[tid] : 0;
        sh.scan.s[tid] = v;
        __syncthreads();
        for (int d = 1; d < 256; d <<= 1) {
            int x2 = sh.scan.s[tid];
            if (tid >= d) x2 += sh.scan.s[tid - d];
            __syncthreads();
            sh.scan.s[tid] = x2;
            __syncthreads();
        }
        int excl = sh.scan.s[tid] - v;
        if (tid < p.NB) { p.bucket_base[tid] = excl; p.bucket_cursor[tid] = excl; }
        if (tid == 0) p.bucket_base[p.NB] = sh.scan.s[255];
    }
    grid.sync();

    // P3: scatter edges into bucket-contiguous packed list
    if (bid < pb) {
        sh.sc.h[tid] = 0;
        __syncthreads();
        const int stride = pb * 256;
        for (int e = bid * 256 + tid; e < p.E; e += stride)
            atomicAdd(&sh.sc.h[p.col[e] >> BSH], 1);
        __syncthreads();
        {
            int c = sh.sc.h[tid];
            sh.sc.cur[tid] = (tid < p.NB && c > 0) ? atomicAdd(&p.bucket_cursor[tid], c) : 0;
        }
        __syncthreads();
        for (int e = bid * 256 + tid; e < p.E; e += stride) {
            int c = p.col[e];
            int pos = atomicAdd(&sh.sc.cur[c >> BSH], 1);
            p.pairbuf[pos] = (p.row[e] & 0xFFFF) | ((c & (BSZ - 1)) << 16);
        }
    }
    grid.sync();

    // P4: per-bucket fine CSR build (LDS atomics only)
    for (int b = bid; b < p.NB; b += nblk) {
        const int nd0 = b << BSH;
        const int e0 = p.bucket_base[b];
        const int e1 = p.bucket_base[b + 1];
        sh.bc.lcnt[tid] = 0;
        __syncthreads();
        for (int e = e0 + tid; e < e1; e += 256)
            atomicAdd(&sh.bc.lcnt[(p.pairbuf[e] >> 16) & (BSZ - 1)], 1);
        __syncthreads();
        int v = sh.bc.lcnt[tid];
        sh.bc.ssc[tid] = v;
        __syncthreads();
        for (int d = 1; d < 256; d <<= 1) {
            int x2 = sh.bc.ssc[tid];
            if (tid >= d) x2 += sh.bc.ssc[tid - d];
            __syncthreads();
            sh.bc.ssc[tid] = x2;
            __syncthreads();
        }
        int excl = sh.bc.ssc[tid] - v;
        sh.bc.lcur[tid] = e0 + excl;
        int node = nd0 + tid;
        if (node < p.N) {
            p.rowptr[node] = e0 + excl;
            p.cnt[node]    = v;
            p.dinv[node]   = rsqrtf((float)(v + 1));
        }
        __syncthreads();
        for (int e = e0 + tid; e < e1; e += 256) {
            int pr = p.pairbuf[e];
            int pos = atomicAdd(&sh.bc.lcur[(pr >> 16) & (BSZ - 1)], 1);
            p.csr[pos] = pr & 0xFFFF;
        }
        __syncthreads();
    }
    grid.sync();

    // P5..P10: three GCN layers (gemm + gather), same numerics as round 4
    gemm_phase<128, false, false>(sh, p.x, p.W1, p.dinv, p.bufA, p.N);
    grid.sync();
    gather_phase<true, true>(p.bufA, p.csr, p.rowptr, p.cnt, p.dinv, p.b1, p.bufB, p.N);
    grid.sync();
    gemm_phase<64, true, true>(sh, p.bufB, p.W2, p.dinv, p.bufA, p.N);
    grid.sync();
    gather_phase<false, true>(p.bufA, p.csr, p.rowptr, p.cnt, p.dinv, p.b2, p.bufB, p.N);
    grid.sync();
    gemm_phase<64, true, true>(sh, p.bufB, p.W3, p.dinv, p.bufA, p.N);
    grid.sync();
    gather_phase<false, false>(p.bufA, p.csr, p.rowptr, p.cnt, p.dinv, p.b3, p.node_emb, p.N);
    grid.sync();

    // P11: pooling (run-length batched atomics)
    {
        const int NPW = 16;
        const int lane = tid & 63;
        const int gw = bid * 4 + (tid >> 6);
        const int nw = nblk * 4;
        const int nwk = (p.N + NPW - 1) / NPW;
        for (int w2 = gw; w2 < nwk; w2 += nw) {
            int start = w2 * NPW;
            int end = start + NPW; if (end > p.N) end = p.N;
            int cur = p.batch[start];
            float acc = 0.f; int runlen = 0;
            for (int node = start; node < end; ++node) {
                int g = p.batch[node];
                if (g != cur) {
                    atomicAdd(&p.sums[(size_t)cur * HH + lane], acc);
                    if (lane == 0) atomicAdd(&p.cnts[cur], (float)runlen);
                    acc = 0.f; runlen = 0; cur = g;
                }
                acc += p.node_emb[(size_t)node * HH + lane];
                ++runlen;
            }
            atomicAdd(&p.sums[(size_t)cur * HH + lane], acc);
            if (lane == 0) atomicAdd(&p.cnts[cur], (float)runlen);
        }
    }
    grid.sync();

    // P12: classifier + softmax
    for (int g = bid; g < p.G; g += nblk) {
        __syncthreads();
        if (tid < HH) {
            float mean = p.sums[(size_t)g * HH + tid] / fmaxf(p.cnts[g], 1.0f);
            p.graph_emb[(size_t)g * HH + tid] = mean;
            sh.fin.semb[tid] = mean;
        }
        __syncthreads();
        if (tid < 10) {
            float acc = p.bm[tid];
            for (int k = 0; k < HH; ++k) acc = fmaf(sh.fin.semb[k], p.Wm[k * 10 + tid], acc);
            sh.fin.slog[tid] = acc;
        }
        __syncthreads();
        if (tid < 10) {
            float mx = -1e30f;
            for (int j = 0; j < 10; ++j) mx = fmaxf(mx, sh.fin.slog[j]);
            float den = 0.f;
            for (int j = 0; j < 10; ++j) den += __expf(sh.fin.slog[j] - mx);
            float lg = sh.fin.slog[tid];
            p.logits[g * 10 + tid] = lg;
            p.probs[g * 10 + tid] = __expf(lg - mx) / den;
        }
    }
}

// ---------------- launch ----------------

extern "C" void kernel_launch(void* const* d_in, const int* in_sizes, int n_in,
                              void* d_out, int out_size, void* d_ws, size_t ws_size,
                              hipStream_t stream) {
    Params p;
    p.x     = (const float*)d_in[0];
    const int* ei = (const int*)d_in[1];
    p.batch = (const int*)d_in[2];
    p.W1 = (const float*)d_in[3];  p.b1 = (const float*)d_in[4];
    p.W2 = (const float*)d_in[5];  p.b2 = (const float*)d_in[6];
    p.W3 = (const float*)d_in[7];  p.b3 = (const float*)d_in[8];
    p.Wm = (const float*)d_in[9];  p.bm = (const float*)d_in[10];

    p.N = in_sizes[2];
    p.E = in_sizes[1] / 2;
    p.G = (out_size - p.N * HH) / (2 * 10 + HH);
    p.NB = (p.N + BSZ - 1) >> BSH;

    p.row = ei;
    p.col = ei + p.E;

    float* out   = (float*)d_out;
    p.logits     = out;
    p.probs      = out + (size_t)p.G * 10;
    p.node_emb   = out + (size_t)2 * p.G * 10;
    p.graph_emb  = p.node_emb + (size_t)p.N * HH;

    char* w = (char*)d_ws;
    auto alloc = [&](size_t bytes) { char* q = w; w += (bytes + 255) & ~(size_t)255; return q; };
    p.dinv          = (float*)alloc((size_t)p.N * 4);
    p.cnt           = (int*)  alloc((size_t)p.N * 4);
    p.rowptr        = (int*)  alloc((size_t)p.N * 4);
    p.bucket_cnt    = (int*)  alloc((size_t)(p.NB + 1) * 4);
    p.bucket_base   = (int*)  alloc((size_t)(p.NB + 1) * 4);
    p.bucket_cursor = (int*)  alloc((size_t)(p.NB + 1) * 4);
    p.sums          = (float*)alloc((size_t)p.G * HH * 4 + (size_t)p.G * 4);
    p.cnts          = p.sums + (size_t)p.G * HH;
    p.pairbuf       = (int*)  alloc((size_t)p.E * 4);
    p.csr           = (int*)  alloc((size_t)p.E * 4);
    p.bufA          = (half_t*)alloc((size_t)p.N * HH * 2);
    p.bufB          = (half_t*)alloc((size_t)p.N * HH * 2);

    // Cooperative launch: 4 blocks/CU guaranteed by __launch_bounds__(256,4)
    // (LDS 16.9 KB/block, VGPR capped at 128). Clamp via occupancy query.
    int maxb = 4;
    (void)hipOccupancyMaxActiveBlocksPerMultiprocessor(&maxb, mega, 256, 0);
    if (maxb > 4) maxb = 4;
    if (maxb < 1) maxb = 1;
    int gridBlocks = 256 * maxb;   // 256 CUs on MI355X

    void* kargs[] = { (void*)&p };
    (void)hipLaunchCooperativeKernel((void*)mega, dim3(gridBlocks), dim3(256),
                                     kargs, 0, stream);
}

// Round 6
// 269.944 us; speedup vs baseline: 4.9021x; 4.9021x over previous
//
#include <hip/hip_runtime.h>
#include <math.h>

#define HH 64
// Bucket = col >> 8 (256 nodes per bucket). Requires N <= 65536 (N=50000 here),
// also required by the 16-bit row packing in pairbuf, and NB <= 256.
#define BSH 8
#define BSZ 256
#define HBLK 256                       // blocks participating in histogram/scatter
#define HSTRIDE (HBLK * 256)           // edge-slice stride (must match in both passes)

typedef _Float16 half_t;
typedef _Float16 half4_t __attribute__((ext_vector_type(4)));

// ---------------- layer-1 GEMM (fp32 x @ W1 -> fp16) + bucket histogram -------
// Blocks 0..HBLK-1 additionally compute a per-block bucket histogram of col[]
// into ph[bid][bucket] (pure overwrite -> no zero-init kernel, no global atomics).
__global__ __launch_bounds__(256, 3)
void k_gemm1_hist(const float* __restrict__ x, const float* __restrict__ W,
                  half_t* __restrict__ out, int n,
                  const int* __restrict__ col, int E, int* __restrict__ ph) {
    constexpr int FIN = 128;
    constexpr int KC = 32;
    __shared__ __align__(16) float Ws[FIN][HH];
    __shared__ __align__(16) float xs_t[KC][68];
    __shared__ int hh[BSZ];
    const int tid = threadIdx.x;
    const int bid = blockIdx.x;

    // ---- histogram slice (blocks 0..HBLK-1) ----
    if (bid < HBLK) {
        hh[tid] = 0;
        __syncthreads();
        for (int e = bid * 256 + tid; e < E; e += HSTRIDE)
            atomicAdd(&hh[col[e] >> BSH], 1);
        __syncthreads();
        ph[bid * BSZ + tid] = hh[tid];
    }

    // ---- GEMM tile (verified round-4 structure) ----
    const int tx = tid & 15;
    const int ty = tid >> 4;
    const int node0 = bid * 64;
    if (node0 >= n) return;

    for (int i = tid * 4; i < FIN * HH; i += 1024)
        *(float4*)&Ws[0][i] = *(const float4*)&W[i];

    float acc[4][4] = {};
    const int rr0 = tid >> 3;
    const int cc  = (tid & 7) * 4;

    for (int kc = 0; kc < FIN; kc += KC) {
        __syncthreads();
        for (int rr = rr0; rr < 64; rr += 32) {
            float4 v = make_float4(0.f, 0.f, 0.f, 0.f);
            if (node0 + rr < n) v = *(const float4*)&x[(size_t)(node0 + rr) * FIN + kc + cc];
            xs_t[cc + 0][rr] = v.x;
            xs_t[cc + 1][rr] = v.y;
            xs_t[cc + 2][rr] = v.z;
            xs_t[cc + 3][rr] = v.w;
        }
        __syncthreads();
#pragma unroll 4
        for (int k = 0; k < KC; ++k) {
            float4 a4 = *(const float4*)&xs_t[k][ty * 4];
            float4 b4 = *(const float4*)&Ws[kc + k][tx * 4];
            acc[0][0] = fmaf(a4.x, b4.x, acc[0][0]);
            acc[0][1] = fmaf(a4.x, b4.y, acc[0][1]);
            acc[0][2] = fmaf(a4.x, b4.z, acc[0][2]);
            acc[0][3] = fmaf(a4.x, b4.w, acc[0][3]);
            acc[1][0] = fmaf(a4.y, b4.x, acc[1][0]);
            acc[1][1] = fmaf(a4.y, b4.y, acc[1][1]);
            acc[1][2] = fmaf(a4.y, b4.z, acc[1][2]);
            acc[1][3] = fmaf(a4.y, b4.w, acc[1][3]);
            acc[2][0] = fmaf(a4.z, b4.x, acc[2][0]);
            acc[2][1] = fmaf(a4.z, b4.y, acc[2][1]);
            acc[2][2] = fmaf(a4.z, b4.z, acc[2][2]);
            acc[2][3] = fmaf(a4.z, b4.w, acc[2][3]);
            acc[3][0] = fmaf(a4.w, b4.x, acc[3][0]);
            acc[3][1] = fmaf(a4.w, b4.y, acc[3][1]);
            acc[3][2] = fmaf(a4.w, b4.z, acc[3][2]);
            acc[3][3] = fmaf(a4.w, b4.w, acc[3][3]);
        }
    }
#pragma unroll
    for (int i = 0; i < 4; ++i) {
        int node = node0 + ty * 4 + i;
        if (node < n) {
            half4_t o = {(half_t)acc[i][0], (half_t)acc[i][1],
                         (half_t)acc[i][2], (half_t)acc[i][3]};
            *(half4_t*)(out + (size_t)node * HH + tx * 4) = o;
        }
    }
}

// ---------------- scatter: atomic-free via ph-prefix; folds in the bucket scan ----
// Block b: for bucket t, before = sum_{k<b} ph[k][t], total = sum_all ph[k][t];
// LDS-scan totals -> base; block's exact slot range = base[t]+before .. +ph[b][t].
// Block 0 also publishes base[] for k_bcsr. Fully deterministic across blocks.
__global__ __launch_bounds__(256) void k_bscatter2(const int* __restrict__ row,
                                                   const int* __restrict__ col, int E,
                                                   const int* __restrict__ ph,
                                                   int* __restrict__ base,
                                                   int* __restrict__ pair, int nb) {
    __shared__ int cur[BSZ];
    __shared__ int ssc[BSZ];
    const int b = blockIdx.x;
    const int t = threadIdx.x;
    int before = 0, total = 0;
    for (int k = 0; k < HBLK; ++k) {
        int v = ph[k * BSZ + t];
        total += v;
        if (k < b) before += v;
    }
    ssc[t] = total;
    __syncthreads();
    for (int d = 1; d < 256; d <<= 1) {
        int x2 = ssc[t];
        if (t >= d) x2 += ssc[t - d];
        __syncthreads();
        ssc[t] = x2;
        __syncthreads();
    }
    int excl = ssc[t] - total;
    cur[t] = excl + before;
    if (b == 0) {
        if (t < nb) base[t] = excl;
        if (t == 0) base[nb] = E;      // all edges land in buckets < nb
    }
    __syncthreads();
    for (int e = b * 256 + t; e < E; e += HSTRIDE) {
        int c = col[e];
        int pos = atomicAdd(&cur[c >> BSH], 1);   // LDS atomic only
        pair[pos] = (row[e] & 0xFFFF) | ((c & (BSZ - 1)) << 16);
    }
}

// ---------------- per-bucket fine CSR build (unchanged, round-4 verified) -----
__global__ __launch_bounds__(256) void k_bcsr(const int* __restrict__ pair,
                                              const int* __restrict__ base,
                                              int* __restrict__ rowptr,
                                              int* __restrict__ cnt,
                                              float* __restrict__ dinv,
                                              int* __restrict__ csr, int n) {
    __shared__ int lcnt[BSZ];
    __shared__ int ssc[BSZ];
    __shared__ int lcur[BSZ];
    const int b = blockIdx.x;
    const int t = threadIdx.x;
    const int nd0 = b << BSH;
    const int e0 = base[b];
    const int e1 = base[b + 1];

    lcnt[t] = 0;
    __syncthreads();
    for (int e = e0 + t; e < e1; e += 256)
        atomicAdd(&lcnt[(pair[e] >> 16) & (BSZ - 1)], 1);
    __syncthreads();
    int v = lcnt[t];
    ssc[t] = v;
    __syncthreads();
    for (int d = 1; d < 256; d <<= 1) {
        int x2 = ssc[t];
        if (t >= d) x2 += ssc[t - d];
        __syncthreads();
        ssc[t] = x2;
        __syncthreads();
    }
    int excl = ssc[t] - v;
    lcur[t] = e0 + excl;
    int node = nd0 + t;
    if (node < n) {
        rowptr[node] = e0 + excl;
        cnt[node]    = v;
        dinv[node]   = rsqrtf((float)(v + 1));
    }
    __syncthreads();
    for (int e = e0 + t; e < e1; e += 256) {
        int pr = pair[e];
        int pos = atomicAdd(&lcur[(pr >> 16) & (BSZ - 1)], 1);
        csr[pos] = pr & 0xFFFF;
    }
}

// ---------------- dense transform layers 2-3 (fp16 in/out, round-4 verified) ---
template<int FIN>
__global__ __launch_bounds__(256, 4)
void k_gemm(const half_t* __restrict__ xin, const float* __restrict__ W,
            const float* __restrict__ dinv, half_t* __restrict__ out, int n) {
    constexpr int KC = 32;
    __shared__ __align__(16) float Ws[FIN][HH];
    __shared__ __align__(16) float xs_t[KC][68];
    const int tid = threadIdx.x;
    const int tx = tid & 15;
    const int ty = tid >> 4;
    const int node0 = blockIdx.x * 64;
    if (node0 >= n) return;

    for (int i = tid * 4; i < FIN * HH; i += 1024)
        *(float4*)&Ws[0][i] = *(const float4*)&W[i];

    float acc[4][4] = {};
    const int rr0 = tid >> 3;
    const int cc  = (tid & 7) * 4;

    for (int kc = 0; kc < FIN; kc += KC) {
        __syncthreads();
        for (int rr = rr0; rr < 64; rr += 32) {
            float4 v = make_float4(0.f, 0.f, 0.f, 0.f);
            if (node0 + rr < n) {
                half4_t hv = *(const half4_t*)(xin + (size_t)(node0 + rr) * FIN + kc + cc);
                v = make_float4((float)hv.x, (float)hv.y, (float)hv.z, (float)hv.w);
            }
            xs_t[cc + 0][rr] = v.x;
            xs_t[cc + 1][rr] = v.y;
            xs_t[cc + 2][rr] = v.z;
            xs_t[cc + 3][rr] = v.w;
        }
        __syncthreads();
#pragma unroll 4
        for (int k = 0; k < KC; ++k) {
            float4 a4 = *(const float4*)&xs_t[k][ty * 4];
            float4 b4 = *(const float4*)&Ws[kc + k][tx * 4];
            acc[0][0] = fmaf(a4.x, b4.x, acc[0][0]);
            acc[0][1] = fmaf(a4.x, b4.y, acc[0][1]);
            acc[0][2] = fmaf(a4.x, b4.z, acc[0][2]);
            acc[0][3] = fmaf(a4.x, b4.w, acc[0][3]);
            acc[1][0] = fmaf(a4.y, b4.x, acc[1][0]);
            acc[1][1] = fmaf(a4.y, b4.y, acc[1][1]);
            acc[1][2] = fmaf(a4.y, b4.z, acc[1][2]);
            acc[1][3] = fmaf(a4.y, b4.w, acc[1][3]);
            acc[2][0] = fmaf(a4.z, b4.x, acc[2][0]);
            acc[2][1] = fmaf(a4.z, b4.y, acc[2][1]);
            acc[2][2] = fmaf(a4.z, b4.z, acc[2][2]);
            acc[2][3] = fmaf(a4.z, b4.w, acc[2][3]);
            acc[3][0] = fmaf(a4.w, b4.x, acc[3][0]);
            acc[3][1] = fmaf(a4.w, b4.y, acc[3][1]);
            acc[3][2] = fmaf(a4.w, b4.z, acc[3][2]);
            acc[3][3] = fmaf(a4.w, b4.w, acc[3][3]);
        }
    }
#pragma unroll
    for (int i = 0; i < 4; ++i) {
        int node = node0 + ty * 4 + i;
        if (node < n) {
            float d = dinv[node];
            half4_t o = {(half_t)(acc[i][0] * d), (half_t)(acc[i][1] * d),
                         (half_t)(acc[i][2] * d), (half_t)(acc[i][3] * d)};
            *(half4_t*)(out + (size_t)node * HH + tx * 4) = o;
        }
    }
}

// ---------------- gather: quarter-wave, fp16 rows, fp32 accumulate (round-4) ---
template<bool WEIGHTED, bool HOUT>
__global__ __launch_bounds__(256) void k_gather_q(const half_t* __restrict__ lin,
                                                  const int* __restrict__ csr,
                                                  const int* __restrict__ rowptr,
                                                  const int* __restrict__ cnt,
                                                  const float* __restrict__ dinv,
                                                  const float* __restrict__ b,
                                                  void* __restrict__ hout, int n) {
    int node = blockIdx.x * 4 + (threadIdx.x >> 6);
    int lane = threadIdx.x & 63;
    if (node >= n) return;
    const int q  = lane >> 4;
    const int fl = (lane & 15) * 4;
    int start = rowptr[node];
    int end = start + cnt[node];
    float di = dinv[node];

    float4 a0 = make_float4(0.f, 0.f, 0.f, 0.f);
    float4 a1 = make_float4(0.f, 0.f, 0.f, 0.f);

    for (int base = start; base < end; base += 64) {
        int m = end - base; if (m > 64) m = 64;
        int idx = base + lane;
        int   sv = (idx < end) ? csr[idx] : 0;
        float wv;
        if (WEIGHTED) wv = (idx < end) ? dinv[sv] : 0.f;
        else          wv = (idx < end) ? 1.f : 0.f;
        for (int j = 0; j < m; j += 16) {
            int l = j + q * 4;
            int   s0 = __shfl(sv, l, 64);
            int   s1 = __shfl(sv, l + 1, 64);
            int   s2 = __shfl(sv, l + 2, 64);
            int   s3 = __shfl(sv, l + 3, 64);
            float w0 = __shfl(wv, l, 64);
            float w1 = __shfl(wv, l + 1, 64);
            float w2 = __shfl(wv, l + 2, 64);
            float w3 = __shfl(wv, l + 3, 64);
            half4_t v0 = *(const half4_t*)&lin[(size_t)s0 * HH + fl];
            half4_t v1 = *(const half4_t*)&lin[(size_t)s1 * HH + fl];
            half4_t v2 = *(const half4_t*)&lin[(size_t)s2 * HH + fl];
            half4_t v3 = *(const half4_t*)&lin[(size_t)s3 * HH + fl];
            a0.x = fmaf(w0, (float)v0.x, a0.x); a0.y = fmaf(w0, (float)v0.y, a0.y);
            a0.z = fmaf(w0, (float)v0.z, a0.z); a0.w = fmaf(w0, (float)v0.w, a0.w);
            a1.x = fmaf(w1, (float)v1.x, a1.x); a1.y = fmaf(w1, (float)v1.y, a1.y);
            a1.z = fmaf(w1, (float)v1.z, a1.z); a1.w = fmaf(w1, (float)v1.w, a1.w);
            a0.x = fmaf(w2, (float)v2.x, a0.x); a0.y = fmaf(w2, (float)v2.y, a0.y);
            a0.z = fmaf(w2, (float)v2.z, a0.z); a0.w = fmaf(w2, (float)v2.w, a0.w);
            a1.x = fmaf(w3, (float)v3.x, a1.x); a1.y = fmaf(w3, (float)v3.y, a1.y);
            a1.z = fmaf(w3, (float)v3.z, a1.z); a1.w = fmaf(w3, (float)v3.w, a1.w);
        }
    }
    float4 acc = make_float4(a0.x + a1.x, a0.y + a1.y, a0.z + a1.z, a0.w + a1.w);
#pragma unroll
    for (int off = 16; off < 64; off <<= 1) {
        acc.x += __shfl_xor(acc.x, off, 64);
        acc.y += __shfl_xor(acc.y, off, 64);
        acc.z += __shfl_xor(acc.z, off, 64);
        acc.w += __shfl_xor(acc.w, off, 64);
    }
    half4_t self = *(const half4_t*)&lin[(size_t)node * HH + fl];
    float sw = WEIGHTED ? di : 1.f;
    acc.x = fmaf(sw, (float)self.x, acc.x);
    acc.y = fmaf(sw, (float)self.y, acc.y);
    acc.z = fmaf(sw, (float)self.z, acc.z);
    acc.w = fmaf(sw, (float)self.w, acc.w);
    float4 b4 = *(const float4*)&b[fl];
    float4 v4 = make_float4(fmaf(di, acc.x, b4.x), fmaf(di, acc.y, b4.y),
                            fmaf(di, acc.z, b4.z), fmaf(di, acc.w, b4.w));
    float ss = v4.x * v4.x + v4.y * v4.y + v4.z * v4.z + v4.w * v4.w;
#pragma unroll
    for (int off = 1; off < 16; off <<= 1) ss += __shfl_xor(ss, off, 64);
    float inv = 1.f / fmaxf(sqrtf(ss), 1e-12f);
    v4.x = fmaxf(v4.x * inv, 0.f);
    v4.y = fmaxf(v4.y * inv, 0.f);
    v4.z = fmaxf(v4.z * inv, 0.f);
    v4.w = fmaxf(v4.w * inv, 0.f);
    if (q == 0) {
        if constexpr (HOUT) {
            half4_t o = {(half_t)v4.x, (half_t)v4.y, (half_t)v4.z, (half_t)v4.w};
            *(half4_t*)((half_t*)hout + (size_t)node * HH + fl) = o;
        } else {
            *(float4*)((float*)hout + (size_t)node * HH + fl) = v4;
        }
    }
}

// ---------------- fused pool + classifier: one block per graph, no atomics ----
// batch is sorted -> binary-search the node range of graph g; direct sum.
__global__ __launch_bounds__(256) void k_poolfinal(const float* __restrict__ node_emb,
                                                   const int* __restrict__ batch,
                                                   const float* __restrict__ Wm,
                                                   const float* __restrict__ bm,
                                                   float* __restrict__ logits,
                                                   float* __restrict__ probs,
                                                   float* __restrict__ graph_emb, int n) {
    __shared__ float part[4][HH];
    __shared__ float semb[HH];
    __shared__ float slog[16];
    const int g = blockIdx.x;
    const int tid = threadIdx.x;
    const int lane = tid & 63, w = tid >> 6;

    int lo = 0, hi = n;
    while (lo < hi) { int mid = (lo + hi) >> 1; if (batch[mid] < g) lo = mid + 1; else hi = mid; }
    const int s = lo;
    hi = n;
    while (lo < hi) { int mid = (lo + hi) >> 1; if (batch[mid] < g + 1) lo = mid + 1; else hi = mid; }
    const int e2 = lo;

    float acc = 0.f;
    for (int i = s + w; i < e2; i += 4) acc += node_emb[(size_t)i * HH + lane];
    part[w][lane] = acc;
    __syncthreads();
    if (tid < HH) {
        float m = part[0][tid] + part[1][tid] + part[2][tid] + part[3][tid];
        m /= fmaxf((float)(e2 - s), 1.f);
        graph_emb[(size_t)g * HH + tid] = m;
        semb[tid] = m;
    }
    __syncthreads();
    if (tid < 10) {
        float a2 = bm[tid];
        for (int k = 0; k < HH; ++k) a2 = fmaf(semb[k], Wm[k * 10 + tid], a2);
        slog[tid] = a2;
    }
    __syncthreads();
    if (tid < 10) {
        float mx = -1e30f;
        for (int j = 0; j < 10; ++j) mx = fmaxf(mx, slog[j]);
        float den = 0.f;
        for (int j = 0; j < 10; ++j) den += __expf(slog[j] - mx);
        float lg = slog[tid];
        logits[g * 10 + tid] = lg;
        probs[g * 10 + tid] = __expf(lg - mx) / den;
    }
}

// ---------------- launch ----------------

extern "C" void kernel_launch(void* const* d_in, const int* in_sizes, int n_in,
                              void* d_out, int out_size, void* d_ws, size_t ws_size,
                              hipStream_t stream) {
    const float* x     = (const float*)d_in[0];
    const int*   ei    = (const int*)  d_in[1];
    const int*   batch = (const int*)  d_in[2];
    const float* W1 = (const float*)d_in[3];  const float* b1 = (const float*)d_in[4];
    const float* W2 = (const float*)d_in[5];  const float* b2 = (const float*)d_in[6];
    const float* W3 = (const float*)d_in[7];  const float* b3 = (const float*)d_in[8];
    const float* Wm = (const float*)d_in[9];  const float* bm = (const float*)d_in[10];

    const int N = in_sizes[2];
    const int E = in_sizes[1] / 2;
    const int G = (out_size - N * HH) / (2 * 10 + HH);
    const int NB = (N + BSZ - 1) >> BSH;

    const int* row = ei;
    const int* col = ei + E;

    float* out       = (float*)d_out;
    float* logits    = out;
    float* probs     = out + (size_t)G * 10;
    float* node_emb  = out + (size_t)2 * G * 10;
    float* graph_emb = node_emb + (size_t)N * HH;

    char* w = (char*)d_ws;
    auto alloc = [&](size_t bytes) { char* p = w; w += (bytes + 255) & ~(size_t)255; return p; };
    float* dinv    = (float*)alloc((size_t)N * 4);
    int*   cnt     = (int*)  alloc((size_t)N * 4);
    int*   rowptr  = (int*)  alloc((size_t)N * 4);
    int*   ph      = (int*)  alloc((size_t)HBLK * BSZ * 4);
    int*   base    = (int*)  alloc((size_t)(NB + 1) * 4);
    int*   pairbuf = (int*)  alloc((size_t)E * 4);
    int*   csr     = (int*)  alloc((size_t)E * 4);
    half_t* bufA   = (half_t*)alloc((size_t)N * HH * 2);
    half_t* bufB   = (half_t*)alloc((size_t)N * HH * 2);

    const int B = 256;
    dim3 blk(B);
    int node_blocks = (N + 3) / 4;
    int gemm_blocks = (N + 63) / 64;
    int g1_blocks = gemm_blocks > HBLK ? gemm_blocks : HBLK;

    // 9 launches total (was 13): CSR build is 3 kernels, pool+final fused.
    k_gemm1_hist<<<g1_blocks, blk, 0, stream>>>(x, W1, bufA, N, col, E, ph);
    k_bscatter2<<<HBLK, blk, 0, stream>>>(row, col, E, ph, base, pairbuf, NB);
    k_bcsr<<<NB, blk, 0, stream>>>(pairbuf, base, rowptr, cnt, dinv, csr, N);

    k_gather_q<true, true><<<node_blocks, blk, 0, stream>>>(bufA, csr, rowptr, cnt, dinv, b1, bufB, N);
    k_gemm<64><<<gemm_blocks, blk, 0, stream>>>(bufB, W2, dinv, bufA, N);
    k_gather_q<false, true><<<node_blocks, blk, 0, stream>>>(bufA, csr, rowptr, cnt, dinv, b2, bufB, N);
    k_gemm<64><<<gemm_blocks, blk, 0, stream>>>(bufB, W3, dinv, bufA, N);
    k_gather_q<false, false><<<node_blocks, blk, 0, stream>>>(bufA, csr, rowptr, cnt, dinv, b3, node_emb, N);

    k_poolfinal<<<G, blk, 0, stream>>>(node_emb, batch, Wm, bm, logits, probs, graph_emb, N);
}